// Round 2
// 289.209 us; speedup vs baseline: 1.0229x; 1.0229x over previous
//
#include <hip/hip_runtime.h>
#include <math.h>

// Dims: x[8192,4096] A[128,4096] B[8,4096,16] Wr[8,4096] br[8] -> out[8192,4096]
#define D_DIM 4096
#define O_DIM 4096
// GEMM1 virtual weight: rows 0..127 = A, 128..135 = Wr, 136..143 = zero. N1=144.
#define KSPLIT 8

typedef __attribute__((ext_vector_type(8))) short short8;
typedef __attribute__((ext_vector_type(4))) float floatx4;

__device__ inline unsigned short f2bf(float f) {
    union { float f; unsigned u; } v; v.f = f;
    unsigned r = v.u + 0x7FFF + ((v.u >> 16) & 1);   // RNE
    return (unsigned short)(r >> 16);
}

// ---------- prep A: W1bf [144][4096] bf16 from A(128 rows) + Wr(8) + zeros(8) ----------
__global__ __launch_bounds__(256) void k0a_prepW1(const float* __restrict__ A,
                                                  const float* __restrict__ Wr,
                                                  unsigned short* __restrict__ W1bf) {
    int e = (blockIdx.x * 256 + threadIdx.x) * 4;    // 144*4096 = 589824 elems
    int row = e >> 12;
    int col = e & 4095;
    float4 v;
    if (row < 128)      v = *(const float4*)(A + (size_t)row * D_DIM + col);
    else if (row < 136) v = *(const float4*)(Wr + (size_t)(row - 128) * D_DIM + col);
    else                v = make_float4(0.f, 0.f, 0.f, 0.f);
    ushort4 o; o.x = f2bf(v.x); o.y = f2bf(v.y); o.z = f2bf(v.z); o.w = f2bf(v.w);
    *(ushort4*)(W1bf + e) = o;
}

// ---------- prep B: Btbf [4096][128] bf16, Btbf[o][h*16+r] = B[h][o][r] ----------
__global__ __launch_bounds__(256) void k0b_prepBt(const float* __restrict__ B,
                                                  unsigned short* __restrict__ Btbf) {
    int e = (blockIdx.x * 256 + threadIdx.x) * 4;    // 4096*128 = 524288 elems
    int o = e >> 7;
    int k = e & 127;          // k%4==0, so all 4 elems share h
    int h = k >> 4;
    int r = k & 15;
    float4 v = *(const float4*)(B + (size_t)h * (O_DIM * 16) + (size_t)o * 16 + r);
    ushort4 w; w.x = f2bf(v.x); w.y = f2bf(v.y); w.z = f2bf(v.z); w.w = f2bf(v.w);
    *(ushort4*)(Btbf + e) = w;
}

// ---------- GEMM1: P[kslice][8192][144] = x * W1^T (per K-slice), bf16 MFMA ----------
// grid = 128 mblks * KSPLIT(8) = 1024 blocks; block = 256 (4 waves).
// Mtile=64: each wave owns 16 rows x 144 cols (1 x 9 sub-tiles). LDS 29.3 KB -> 5 blocks/CU.
__global__ __launch_bounds__(256) void k1_gemm1(const float* __restrict__ X,
                                                const unsigned short* __restrict__ W1bf,
                                                float* __restrict__ P) {
    __shared__ short Xs[64][72];     // 64 bf16 + 8 pad -> b128 reads spread bank groups
    __shared__ short Ws[144][72];
    const int kslice = blockIdx.x & (KSPLIT - 1);
    const int mblk   = blockIdx.x >> 3;
    const int m0     = mblk * 64;
    const int kbase  = kslice * (D_DIM / KSPLIT);    // 512
    const int tid  = threadIdx.x;
    const int wave = tid >> 6;
    const int lane = tid & 63;
    const int lrow = lane & 15;
    const int quad = lane >> 4;

    floatx4 acc[9];
    #pragma unroll
    for (int n = 0; n < 9; ++n) acc[n] = (floatx4)(0.f);

    for (int it = 0; it < (D_DIM / KSPLIT) / 64; ++it) {   // 8 chunks of BK=64
        const int k0c = kbase + it * 64;
        // stage X: 64x64 fp32 -> bf16.  1024 float4 / 256 thr = 4 each
        #pragma unroll
        for (int i = 0; i < 4; ++i) {
            int e   = tid + i * 256;        // 0..1023
            int row = e >> 4;               // 16 float4 per row
            int c4  = e & 15;
            float4 v = *(const float4*)(X + (size_t)(m0 + row) * D_DIM + k0c + c4 * 4);
            ushort4 o; o.x = f2bf(v.x); o.y = f2bf(v.y); o.z = f2bf(v.z); o.w = f2bf(v.w);
            *(ushort4*)&Xs[row][c4 * 4] = o;
        }
        // stage W: 144x64 bf16.  1152 x 16B / 256 thr = 4.5
        #pragma unroll
        for (int i = 0; i < 5; ++i) {
            int e = tid + i * 256;
            if (e < 1152) {
                int row = e >> 3;           // 8 x16B per row
                int c8  = e & 7;
                uint4 v = *(const uint4*)(W1bf + (size_t)row * D_DIM + k0c + c8 * 8);
                *(uint4*)&Ws[row][c8 * 8] = v;
            }
        }
        __syncthreads();
        #pragma unroll
        for (int ks = 0; ks < 2; ++ks) {    // 2 MFMA k-steps of 32
            const int koff = ks * 32 + quad * 8;
            short8 a = *(const short8*)&Xs[wave * 16 + lrow][koff];
            #pragma unroll
            for (int n = 0; n < 9; ++n) {
                short8 b = *(const short8*)&Ws[n * 16 + lrow][koff];
                acc[n] = __builtin_amdgcn_mfma_f32_16x16x32_bf16(a, b, acc[n], 0, 0, 0);
            }
        }
        __syncthreads();
    }

    float* Pk = P + (size_t)kslice * (8192 * 144);
    #pragma unroll
    for (int n = 0; n < 9; ++n) {
        #pragma unroll
        for (int reg = 0; reg < 4; ++reg) {
            int row = m0 + wave * 16 + quad * 4 + reg;    // C/D: row=(lane>>4)*4+reg
            int col = n * 16 + lrow;                      //      col=lane&15
            Pk[(size_t)row * 144 + col] = acc[n][reg];
        }
    }
}

// ---------- reduce split-K + softmax + scale -> W2 bf16 [8192][128] ----------
// grid = 512 blocks x 16 rows (2 blocks/CU).
__global__ __launch_bounds__(256) void k15_reduce_softmax(const float* __restrict__ P,
                                                          const float* __restrict__ br,
                                                          unsigned short* __restrict__ W2) {
    __shared__ float S[16][148];
    const int t0  = blockIdx.x * 16;
    const int tid = threadIdx.x;
    // sum 8 partials: 16x144 = 576 float4 per partial / 256 thr = 2.25 each
    #pragma unroll
    for (int i = 0; i < 3; ++i) {
        int e = tid + i * 256;
        if (e < 576) {
            int row = e / 36;                 // 36 float4 per row
            int c4  = e - row * 36;
            size_t off = (size_t)(t0 + row) * 144 + c4 * 4;
            float4 s = *(const float4*)(P + off);
            #pragma unroll
            for (int p = 1; p < KSPLIT; ++p) {
                float4 v = *(const float4*)(P + (size_t)p * (8192 * 144) + off);
                s.x += v.x; s.y += v.y; s.z += v.z; s.w += v.w;
            }
            *(float4*)&S[row][c4 * 4] = s;
        }
    }
    __syncthreads();
    if (tid < 16) {
        float l[8]; float m = -1e30f;
        #pragma unroll
        for (int h = 0; h < 8; ++h) { l[h] = S[tid][128 + h] + br[h]; m = fmaxf(m, l[h]); }
        float s = 0.f;
        #pragma unroll
        for (int h = 0; h < 8; ++h) { l[h] = __expf(l[h] - m); s += l[h]; }
        float inv = 16.0f / s;            // H * SCALING = 16
        #pragma unroll
        for (int h = 0; h < 8; ++h) S[tid][136 + h] = l[h] * inv;   // cols 136..143 were pad
    }
    __syncthreads();
    // write W2 bf16: 16x128 elems = 512 ushort4 units / 256 thr = 2
    #pragma unroll
    for (int i = 0; i < 2; ++i) {
        int e   = tid + i * 256;          // 0..511
        int tok = e >> 5;                 // 32 units per row
        int c4  = e & 31;
        int col = c4 * 4;
        float sc = S[tok][136 + (col >> 4)];
        ushort4 o;
        o.x = f2bf(S[tok][col + 0] * sc);
        o.y = f2bf(S[tok][col + 1] * sc);
        o.z = f2bf(S[tok][col + 2] * sc);
        o.w = f2bf(S[tok][col + 3] * sc);
        *(ushort4*)(W2 + (size_t)(t0 + tok) * 128 + col) = o;
    }
}

// ---------- GEMM2: out[8192][4096] = W2[8192][128] * Btbf[4096][128]^T ----------
// grid = 64 mblks x 32 nblks; tile 128x128, K=128 fully staged (B only).
// A-fragments load directly from L2-resident W2 (2 MB) -> LDS 34.8 KB -> 4 blocks/CU.
__global__ __launch_bounds__(256) void k2_gemm2(const unsigned short* __restrict__ W2,
                                                const unsigned short* __restrict__ Btbf,
                                                float* __restrict__ out) {
    __shared__ short Bs[128][136];   // 128 bf16 + 8 pad
    const int nblk = blockIdx.x & 31;
    const int mblk = blockIdx.x >> 5;
    const int m0 = mblk * 128, n0 = nblk * 128;
    const int tid  = threadIdx.x;
    const int wave = tid >> 6;
    const int lane = tid & 63;
    const int lrow = lane & 15;
    const int quad = lane >> 4;

    // stage B tile: 128 rows x 16 x16B-units = 2048 units / 256 thr = 8 each
    #pragma unroll
    for (int i = 0; i < 8; ++i) {
        int e   = tid + i * 256;
        int row = e >> 4;                 // 16 x16B per row (128 bf16 = 256 B)
        int c8  = e & 15;
        *(uint4*)&Bs[row][c8 * 8] = *(const uint4*)(Btbf + (size_t)(n0 + row) * 128 + c8 * 8);
    }
    __syncthreads();

    floatx4 acc[2][8];
    #pragma unroll
    for (int i = 0; i < 2; ++i)
        #pragma unroll
        for (int n = 0; n < 8; ++n) acc[i][n] = (floatx4)(0.f);

    #pragma unroll
    for (int ks = 0; ks < 4; ++ks) {
        const int koff = ks * 32 + quad * 8;
        short8 a[2];
        #pragma unroll
        for (int i = 0; i < 2; ++i)
            a[i] = *(const short8*)(W2 + (size_t)(m0 + wave * 32 + i * 16 + lrow) * 128 + koff);
        #pragma unroll
        for (int n = 0; n < 8; ++n) {
            short8 b = *(const short8*)&Bs[n * 16 + lrow][koff];
            #pragma unroll
            for (int i = 0; i < 2; ++i)
                acc[i][n] = __builtin_amdgcn_mfma_f32_16x16x32_bf16(a[i], b, acc[i][n], 0, 0, 0);
        }
    }

    #pragma unroll
    for (int i = 0; i < 2; ++i) {
        #pragma unroll
        for (int n = 0; n < 8; ++n) {
            #pragma unroll
            for (int reg = 0; reg < 4; ++reg) {
                int row = m0 + wave * 32 + i * 16 + quad * 4 + reg;
                int col = n0 + n * 16 + lrow;
                __builtin_nontemporal_store(acc[i][n][reg], out + (size_t)row * O_DIM + col);
            }
        }
    }
}

extern "C" void kernel_launch(void* const* d_in, const int* in_sizes, int n_in,
                              void* d_out, int out_size, void* d_ws, size_t ws_size,
                              hipStream_t stream) {
    const float* x  = (const float*)d_in[0];
    const float* A  = (const float*)d_in[1];
    const float* B  = (const float*)d_in[2];
    const float* Wr = (const float*)d_in[3];
    const float* br = (const float*)d_in[4];
    float* out = (float*)d_out;

    // ws layout (float units):
    // P:    KSPLIT * 8192 * 144          = 9,437,184 floats
    // W2:   8192*128 bf16                =   524,288 float-slots
    // W1bf: 144*4096 bf16                =   294,912 float-slots
    // Btbf: 4096*128 bf16                =   262,144 float-slots    total ~42.1 MB
    float* ws = (float*)d_ws;
    float*          P     = ws;
    unsigned short* W2    = (unsigned short*)(ws + 9437184);
    unsigned short* W1bf  = (unsigned short*)(ws + 9437184 + 524288);
    unsigned short* Btbf  = (unsigned short*)(ws + 9437184 + 524288 + 294912);

    k0a_prepW1<<<dim3(576), dim3(256), 0, stream>>>(A, Wr, W1bf);
    k0b_prepBt<<<dim3(512), dim3(256), 0, stream>>>(B, Btbf);
    k1_gemm1<<<dim3(128 * KSPLIT), dim3(256), 0, stream>>>(x, W1bf, P);
    k15_reduce_softmax<<<dim3(512), dim3(256), 0, stream>>>(P, br, W2);
    k2_gemm2<<<dim3(64 * 32), dim3(256), 0, stream>>>(W2, Btbf, out);
}

// Round 3
// 270.735 us; speedup vs baseline: 1.0927x; 1.0682x over previous
//
#include <hip/hip_runtime.h>
#include <hip/hip_bf16.h>
#include <math.h>

// Dims: x[8192,4096] A[128,4096] B[8,4096,16] Wr[8,4096] br[8] -> out[8192,4096]
#define D_DIM 4096
#define O_DIM 4096
// GEMM1 virtual weight: rows 0..127 = A, 128..135 = Wr, 136..143 = zero. N1=144.
#define KSPLIT 8

typedef __attribute__((ext_vector_type(8))) short short8;
typedef __attribute__((ext_vector_type(4))) float floatx4;

__device__ inline unsigned short f2bf(float f) {
    union { float f; unsigned u; } v; v.f = f;
    unsigned r = v.u + 0x7FFF + ((v.u >> 16) & 1);   // RNE
    return (unsigned short)(r >> 16);
}

// packed f32x2 -> bf16x2 (compiler lowers to v_cvt_pk_bf16_f32, RNE)
__device__ inline unsigned cvt2(float lo, float hi) {
    __hip_bfloat162 h2 = __float22bfloat162_rn(make_float2(lo, hi));
    union { __hip_bfloat162 h; unsigned u; } c; c.h = h2;
    return c.u;
}

// ---------- merged prep: W1bf [144][4096] bf16 (A,Wr,zeros) + Btbf [4096][128] ----------
__global__ __launch_bounds__(256) void k0_prep(const float* __restrict__ A,
                                               const float* __restrict__ Wr,
                                               const float* __restrict__ B,
                                               unsigned short* __restrict__ W1bf,
                                               unsigned short* __restrict__ Btbf) {
    if (blockIdx.x < 576) {
        int e = (blockIdx.x * 256 + threadIdx.x) * 4;    // 144*4096 = 589824 elems
        int row = e >> 12;
        int col = e & 4095;
        float4 v;
        if (row < 128)      v = *(const float4*)(A + (size_t)row * D_DIM + col);
        else if (row < 136) v = *(const float4*)(Wr + (size_t)(row - 128) * D_DIM + col);
        else                v = make_float4(0.f, 0.f, 0.f, 0.f);
        ushort4 o; o.x = f2bf(v.x); o.y = f2bf(v.y); o.z = f2bf(v.z); o.w = f2bf(v.w);
        *(ushort4*)(W1bf + e) = o;
    } else {
        int e = ((blockIdx.x - 576) * 256 + threadIdx.x) * 4;   // 4096*128 = 524288 elems
        int o = e >> 7;
        int k = e & 127;          // k%4==0, so all 4 elems share h
        int h = k >> 4;
        int r = k & 15;
        float4 v = *(const float4*)(B + (size_t)h * (O_DIM * 16) + (size_t)o * 16 + r);
        ushort4 w; w.x = f2bf(v.x); w.y = f2bf(v.y); w.z = f2bf(v.z); w.w = f2bf(v.w);
        *(ushort4*)(Btbf + e) = w;
    }
}

// ---------- GEMM1: P[kslice][8192][144] = x * W1^T (per K-slice), bf16 MFMA ----------
// grid = 64 mblks * KSPLIT(8) = 512 blocks; block = 256 (4 waves). Mtile=128.
// LDS 39.2 KB -> 4 blocks/CU (grid-limited to 2/CU).
__global__ __launch_bounds__(256) void k1_gemm1(const float* __restrict__ X,
                                                const unsigned short* __restrict__ W1bf,
                                                float* __restrict__ P) {
    __shared__ short Xs[128][72];    // 64 bf16 + 8 pad
    __shared__ short Ws[144][72];
    const int kslice = blockIdx.x & (KSPLIT - 1);
    const int mblk   = blockIdx.x >> 3;
    const int m0     = mblk * 128;
    const int kbase  = kslice * (D_DIM / KSPLIT);    // 512
    const int tid  = threadIdx.x;
    const int wave = tid >> 6;
    const int lane = tid & 63;
    const int lrow = lane & 15;
    const int quad = lane >> 4;

    floatx4 acc[2][9];
    #pragma unroll
    for (int i = 0; i < 2; ++i)
        #pragma unroll
        for (int n = 0; n < 9; ++n) acc[i][n] = (floatx4)(0.f);

    for (int it = 0; it < (D_DIM / KSPLIT) / 64; ++it) {   // 8 chunks of BK=64
        const int k0c = kbase + it * 64;
        // stage X: 128x64 fp32 -> bf16 via cvt_pk.  2048 float4 / 256 thr = 8 each
        #pragma unroll
        for (int i = 0; i < 8; ++i) {
            int e   = tid + i * 256;        // 0..2047
            int row = e >> 4;               // 16 float4 per row
            int c4  = e & 15;
            float4 v = *(const float4*)(X + (size_t)(m0 + row) * D_DIM + k0c + c4 * 4);
            uint2 o; o.x = cvt2(v.x, v.y); o.y = cvt2(v.z, v.w);
            *(uint2*)&Xs[row][c4 * 4] = o;
        }
        // stage W: 144x64 bf16.  1152 x 16B / 256 thr = 4.5
        #pragma unroll
        for (int i = 0; i < 5; ++i) {
            int e = tid + i * 256;
            if (e < 1152) {
                int row = e >> 3;           // 8 x16B per row
                int c8  = e & 7;
                uint4 v = *(const uint4*)(W1bf + (size_t)row * D_DIM + k0c + c8 * 8);
                *(uint4*)&Ws[row][c8 * 8] = v;
            }
        }
        __syncthreads();
        #pragma unroll
        for (int ks = 0; ks < 2; ++ks) {    // 2 MFMA k-steps of 32
            const int koff = ks * 32 + quad * 8;
            short8 a[2];
            #pragma unroll
            for (int i = 0; i < 2; ++i)
                a[i] = *(const short8*)&Xs[wave * 32 + i * 16 + lrow][koff];
            #pragma unroll
            for (int n = 0; n < 9; ++n) {
                short8 b = *(const short8*)&Ws[n * 16 + lrow][koff];
                #pragma unroll
                for (int i = 0; i < 2; ++i)
                    acc[i][n] = __builtin_amdgcn_mfma_f32_16x16x32_bf16(a[i], b, acc[i][n], 0, 0, 0);
            }
        }
        __syncthreads();
    }

    float* Pk = P + (size_t)kslice * (8192 * 144);
    #pragma unroll
    for (int i = 0; i < 2; ++i) {
        #pragma unroll
        for (int n = 0; n < 9; ++n) {
            #pragma unroll
            for (int reg = 0; reg < 4; ++reg) {
                int row = m0 + wave * 32 + i * 16 + quad * 4 + reg;   // C/D: row=(lane>>4)*4+reg
                int col = n * 16 + lrow;                              //      col=lane&15
                Pk[(size_t)row * 144 + col] = acc[i][n][reg];
            }
        }
    }
}

// ---------- reduce split-K + softmax + scale -> W2 bf16 [8192][128] ----------
// grid = 512 blocks x 16 rows (2 blocks/CU).
__global__ __launch_bounds__(256) void k15_reduce_softmax(const float* __restrict__ P,
                                                          const float* __restrict__ br,
                                                          unsigned short* __restrict__ W2) {
    __shared__ float S[16][148];
    const int t0  = blockIdx.x * 16;
    const int tid = threadIdx.x;
    // sum 8 partials: 16x144 = 576 float4 per partial / 256 thr = 2.25 each
    #pragma unroll
    for (int i = 0; i < 3; ++i) {
        int e = tid + i * 256;
        if (e < 576) {
            int row = e / 36;                 // 36 float4 per row
            int c4  = e - row * 36;
            size_t off = (size_t)(t0 + row) * 144 + c4 * 4;
            float4 s = *(const float4*)(P + off);
            #pragma unroll
            for (int p = 1; p < KSPLIT; ++p) {
                float4 v = *(const float4*)(P + (size_t)p * (8192 * 144) + off);
                s.x += v.x; s.y += v.y; s.z += v.z; s.w += v.w;
            }
            *(float4*)&S[row][c4 * 4] = s;
        }
    }
    __syncthreads();
    if (tid < 16) {
        float l[8]; float m = -1e30f;
        #pragma unroll
        for (int h = 0; h < 8; ++h) { l[h] = S[tid][128 + h] + br[h]; m = fmaxf(m, l[h]); }
        float s = 0.f;
        #pragma unroll
        for (int h = 0; h < 8; ++h) { l[h] = __expf(l[h] - m); s += l[h]; }
        float inv = 16.0f / s;            // H * SCALING = 16
        #pragma unroll
        for (int h = 0; h < 8; ++h) S[tid][136 + h] = l[h] * inv;   // cols 136..143 were pad
    }
    __syncthreads();
    // write W2 bf16: 16x128 elems = 512 ushort4 units / 256 thr = 2
    #pragma unroll
    for (int i = 0; i < 2; ++i) {
        int e   = tid + i * 256;          // 0..511
        int tok = e >> 5;                 // 32 units per row
        int c4  = e & 31;
        int col = c4 * 4;
        float sc = S[tok][136 + (col >> 4)];
        ushort4 o;
        o.x = f2bf(S[tok][col + 0] * sc);
        o.y = f2bf(S[tok][col + 1] * sc);
        o.z = f2bf(S[tok][col + 2] * sc);
        o.w = f2bf(S[tok][col + 3] * sc);
        *(ushort4*)(W2 + (size_t)(t0 + tok) * 128 + col) = o;
    }
}

// ---------- GEMM2: out[8192][4096] = W2[8192][128] * Btbf[4096][128]^T ----------
// grid = 64 mblks x 32 nblks; tile 128x128, K=128 fully staged (B only).
// A-fragments direct from L2-resident W2. Epilogue: LDS-bounce (union w/ dead Bs)
// -> coalesced 512B dwordx4 nontemporal stores. LDS 34.8 KB -> 4 blocks/CU.
__global__ __launch_bounds__(256) void k2_gemm2(const unsigned short* __restrict__ W2,
                                                const unsigned short* __restrict__ Btbf,
                                                float* __restrict__ out) {
    __shared__ union {
        short Bs[128][136];   // 34816 B
        float Sf[64][132];    // 33792 B
    } sm;
    const int nblk = blockIdx.x & 31;
    const int mblk = blockIdx.x >> 5;
    const int m0 = mblk * 128, n0 = nblk * 128;
    const int tid  = threadIdx.x;
    const int wave = tid >> 6;
    const int lane = tid & 63;
    const int lrow = lane & 15;
    const int quad = lane >> 4;

    // stage B tile: 128 rows x 16 x16B-units = 2048 units / 256 thr = 8 each
    #pragma unroll
    for (int i = 0; i < 8; ++i) {
        int e   = tid + i * 256;
        int row = e >> 4;                 // 16 x16B per row (128 bf16 = 256 B)
        int c8  = e & 15;
        *(uint4*)&sm.Bs[row][c8 * 8] = *(const uint4*)(Btbf + (size_t)(n0 + row) * 128 + c8 * 8);
    }
    __syncthreads();

    floatx4 acc[2][8];
    #pragma unroll
    for (int i = 0; i < 2; ++i)
        #pragma unroll
        for (int n = 0; n < 8; ++n) acc[i][n] = (floatx4)(0.f);

    #pragma unroll
    for (int ks = 0; ks < 4; ++ks) {
        const int koff = ks * 32 + quad * 8;
        short8 a[2];
        #pragma unroll
        for (int i = 0; i < 2; ++i)
            a[i] = *(const short8*)(W2 + (size_t)(m0 + wave * 32 + i * 16 + lrow) * 128 + koff);
        #pragma unroll
        for (int n = 0; n < 8; ++n) {
            short8 b = *(const short8*)&sm.Bs[n * 16 + lrow][koff];
            #pragma unroll
            for (int i = 0; i < 2; ++i)
                acc[i][n] = __builtin_amdgcn_mfma_f32_16x16x32_bf16(a[i], b, acc[i][n], 0, 0, 0);
        }
    }
    __syncthreads();   // all MFMA reads of Bs done before reusing as Sf

    // epilogue in 2 halves of 64 rows: C/D layout -> LDS -> coalesced stores
    #pragma unroll
    for (int h = 0; h < 2; ++h) {
        if ((wave >> 1) == h) {           // waves 0,1 own rows 0..63; waves 2,3 rows 64..127
            #pragma unroll
            for (int i = 0; i < 2; ++i)
                #pragma unroll
                for (int n = 0; n < 8; ++n)
                    #pragma unroll
                    for (int reg = 0; reg < 4; ++reg)
                        sm.Sf[(wave & 1) * 32 + i * 16 + quad * 4 + reg][n * 16 + lrow] = acc[i][n][reg];
        }
        __syncthreads();
        #pragma unroll
        for (int i2 = 0; i2 < 8; ++i2) {
            int e   = tid + i2 * 256;     // 0..2047
            int row = e >> 5;             // 32 float4 per row
            int c4  = e & 31;
            floatx4 v = *(const floatx4*)&sm.Sf[row][c4 * 4];
            __builtin_nontemporal_store(v,
                (floatx4*)(out + (size_t)(m0 + h * 64 + row) * O_DIM + n0 + c4 * 4));
        }
        __syncthreads();
    }
}

extern "C" void kernel_launch(void* const* d_in, const int* in_sizes, int n_in,
                              void* d_out, int out_size, void* d_ws, size_t ws_size,
                              hipStream_t stream) {
    const float* x  = (const float*)d_in[0];
    const float* A  = (const float*)d_in[1];
    const float* B  = (const float*)d_in[2];
    const float* Wr = (const float*)d_in[3];
    const float* br = (const float*)d_in[4];
    float* out = (float*)d_out;

    // ws layout (float units):
    // P:    KSPLIT * 8192 * 144          = 9,437,184 floats
    // W2:   8192*128 bf16                =   524,288 float-slots
    // W1bf: 144*4096 bf16                =   294,912 float-slots
    // Btbf: 4096*128 bf16                =   262,144 float-slots    total ~42.1 MB
    float* ws = (float*)d_ws;
    float*          P     = ws;
    unsigned short* W2    = (unsigned short*)(ws + 9437184);
    unsigned short* W1bf  = (unsigned short*)(ws + 9437184 + 524288);
    unsigned short* Btbf  = (unsigned short*)(ws + 9437184 + 524288 + 294912);

    k0_prep<<<dim3(1088), dim3(256), 0, stream>>>(A, Wr, B, W1bf, Btbf);
    k1_gemm1<<<dim3(64 * KSPLIT), dim3(256), 0, stream>>>(x, W1bf, P);
    k15_reduce_softmax<<<dim3(512), dim3(256), 0, stream>>>(P, br, W2);
    k2_gemm2<<<dim3(64 * 32), dim3(256), 0, stream>>>(W2, Btbf, out);
}